// Round 4
// baseline (247.348 us; speedup 1.0000x reference)
//
#include <hip/hip_runtime.h>

// GeometryOptimalTransport: B=4, N=M=4096, C=128
// Sinkhorn (3 iters) over log_K(m,n) = -dist2/eps masked to -1e9, then
// attn-weighted gather of source feats.
//
// R2: validity is iteration-invariant -> precompute adjacency once; run all
// 6 lse updates + output on the ~3% dense structure. Finite NEG_INF=-1e9
// contamination is closed-form:
//   - row with 0 valid entries => u = +1e9 EXACTLY (ulp(1e9)=64)
//   - such rows contribute exp(0) to EVERY column lse => per-batch count cc
//   - all other invalid entries underflow to exactly 0 in fp32.
// R5/R6: compaction (any flavor) costs ~60us -> store permuted bitmap
// directly (bit k of lane L's word <=> partner n=(k>>1)*128+2L+(k&1)).
// R7 result: sweep 61us, VALUBusy 29% ~= pure-VALU floor (14us) -> SIMDs
// idle 70% on VMEM return latency (FETCH ~1MB: loads are cache hits; 8
// blocks/CU stream 32KB arrays through a 32KB L1 and park on vmcnt).
// R8 (this round):
//   (a) sweep7: LDS-stage the 32KB partner tile once per block; inner loop
//       reads ds_read_b128 (short lgkmcnt latency, conflict-free). Masks
//       built as two 32-bit halves (no 64-bit shift chain).
//   (b) output3: XCD-affine row swizzle (row = (xcd>>1)*4096 + slot*2 +
//       (xcd&1)) so each XCD's 4MB L2 caches only its own batch's 2MB of
//       feats instead of all 8MB.

constexpr int   BB = 4;
constexpr int   NN = 4096;
constexpr int   MM = 4096;
constexpr int   CC = 128;
constexpr float kNegInf    = -1000000000.0f;
constexpr float kThresh2   = 0.04f;                 // 0.2^2
constexpr float kNegInvEps = -(1.0f / 0.01000001f); // -(1/(EPSILON+1e-8))

__device__ inline float wave_reduce_max(float x) {
#pragma unroll
  for (int off = 32; off > 0; off >>= 1)
    x = fmaxf(x, __shfl_xor(x, off, 64));
  return x;
}
__device__ inline float wave_reduce_sum(float x) {
#pragma unroll
  for (int off = 32; off > 0; off >>= 1)
    x += __shfl_xor(x, off, 64);
  return x;
}

// ---------------------------------------------------------------------------
// FAST PATH (needs ~17 MB workspace)
// ---------------------------------------------------------------------------

// zero v + empty-row counters, fold masks into locs (invalid -> far sentinel;
// DIFFERENT sentinels per side so two invalid points are never "close").
__global__ __launch_bounds__(256) void prep_kernel(
    const float* __restrict__ sloc, const float* __restrict__ tloc,
    const int* __restrict__ sm, const int* __restrict__ tm,
    float* __restrict__ v, int* __restrict__ ecnt,
    float2* __restrict__ slm, float2* __restrict__ tlm)
{
  int i = blockIdx.x * 256 + threadIdx.x;
  if (i < BB * NN) {
    v[i] = 0.0f;
    float2 s = ((const float2*)sloc)[i];
    slm[i] = sm[i] ? s : make_float2(1.0e9f, 1.0e9f);
    float2 t = ((const float2*)tloc)[i];
    tlm[i] = tm[i] ? t : make_float2(3.0e9f, 3.0e9f);
    if (i < BB) ecnt[i] = 0;
  }
}

// Fused row+col neighbor sweep -> permuted bitmap, LDS-staged partner tile.
// 4 waves/block, 4 rows/wave (16 rows/block). Blocks [0,1024): row side
// (a=tlm vs partners=slm); [1024,2048): col side. Lane L, iter i tests
// partners i*128+2L and i*128+2L+1 (one LDS float4). Bits accumulate via
// 32-bit right-shift halves: after each 16-iter half, iter i's results sit
// at bits 2(i&15)/2(i&15)+1 of the half-word.
__global__ __launch_bounds__(256) void sweep7_kernel(
    const float2* __restrict__ slm, const float2* __restrict__ tlm,
    unsigned long long* __restrict__ row_bm,
    unsigned long long* __restrict__ col_bm,
    int* __restrict__ ecnt)
{
  __shared__ float4 tile4[2048];          // 32 KB: all 4096 partners

  constexpr int RPB = 16;                 // rows per block
  const bool is_row = blockIdx.x < (BB * MM / RPB);
  const int  rbase  = (is_row ? blockIdx.x : blockIdx.x - BB * MM / RPB) * RPB;
  const int  b      = rbase >> 12;        // 4096 % 16 == 0: no batch straddle
  const int  lane   = threadIdx.x & 63;
  const int  wid    = threadIdx.x >> 6;
  const int  tid    = threadIdx.x;
  const int  row0   = rbase + wid * 4;

  const float4* __restrict__ bl4 =
      (const float4*)((is_row ? slm : tlm) + (size_t)b * 4096);
#pragma unroll
  for (int r = 0; r < 8; ++r) tile4[r * 256 + tid] = bl4[r * 256 + tid];

  const float2* __restrict__ ap = (is_row ? tlm : slm);
  const float2 a0 = ap[row0 + 0];
  const float2 a1 = ap[row0 + 1];
  const float2 a2 = ap[row0 + 2];
  const float2 a3 = ap[row0 + 3];
  __syncthreads();

  unsigned lo0, lo1, lo2, lo3, hi0, hi1, hi2, hi3;
#pragma unroll
  for (int half = 0; half < 2; ++half) {
    unsigned m0 = 0, m1 = 0, m2 = 0, m3 = 0;
#pragma unroll 8
    for (int i = 0; i < 16; ++i) {
      float4 q = tile4[(half * 16 + i) * 64 + lane];
#define SWTEST(aa, mm)                                             \
      do {                                                         \
        float dx0 = (aa).x - q.x, dy0 = (aa).y - q.y;              \
        float dx1 = (aa).x - q.z, dy1 = (aa).y - q.w;              \
        bool p0 = fmaf(dy0, dy0, dx0 * dx0) < kThresh2;            \
        bool p1 = fmaf(dy1, dy1, dx1 * dx1) < kThresh2;            \
        mm = (mm >> 2) | (p0 ? (1u << 30) : 0u)                    \
                       | (p1 ? (1u << 31) : 0u);                   \
      } while (0)
      SWTEST(a0, m0);
      SWTEST(a1, m1);
      SWTEST(a2, m2);
      SWTEST(a3, m3);
#undef SWTEST
    }
    if (half == 0) { lo0 = m0; lo1 = m1; lo2 = m2; lo3 = m3; }
    else           { hi0 = m0; hi1 = m1; hi2 = m2; hi3 = m3; }
  }

  const unsigned long long w0 = (unsigned long long)lo0 | ((unsigned long long)hi0 << 32);
  const unsigned long long w1 = (unsigned long long)lo1 | ((unsigned long long)hi1 << 32);
  const unsigned long long w2 = (unsigned long long)lo2 | ((unsigned long long)hi2 << 32);
  const unsigned long long w3 = (unsigned long long)lo3 | ((unsigned long long)hi3 << 32);

  unsigned long long* __restrict__ bm = (is_row ? row_bm : col_bm);
  bm[(size_t)(row0 + 0) * 64 + lane] = w0;
  bm[(size_t)(row0 + 1) * 64 + lane] = w1;
  bm[(size_t)(row0 + 2) * 64 + lane] = w2;
  bm[(size_t)(row0 + 3) * 64 + lane] = w3;

  if (is_row) {
    // empty-row census for the contamination count cc
    unsigned long long z0 = __ballot(w0 != 0ull);
    unsigned long long z1 = __ballot(w1 != 0ull);
    unsigned long long z2 = __ballot(w2 != 0ull);
    unsigned long long z3 = __ballot(w3 != 0ull);
    if (lane == 0) {
      int e = (z0 == 0ull) + (z1 == 0ull) + (z2 == 0ull) + (z3 == 0ull);
      if (e) atomicAdd(&ecnt[b], e);
    }
  }
}

// u[row] = -log(sum_j exp(logK_j + v[n_j])), +1e9 if no valid entries.
// One wave per row; lane L ctz-enumerates its own bitmap word. No max pass:
// all t bounded (|t| << 87), exp cannot over/underflow.
__global__ __launch_bounds__(256) void lse_row_kernel(
    const float2* __restrict__ tlm, const float2* __restrict__ slm,
    const unsigned long long* __restrict__ row_bm,
    const float* __restrict__ v, float* __restrict__ u)
{
  const int lane = threadIdx.x & 63;
  const int row  = blockIdx.x * 4 + (threadIdx.x >> 6);
  const int b    = row >> 12;
  unsigned long long w = row_bm[(size_t)row * 64 + lane];
  const float2 a = tlm[row];
  const float2* __restrict__ sl = slm + (size_t)b * NN;
  const float*  __restrict__ vb = v + (size_t)b * NN;
  float s_l = 0.0f;
  while (w) {
    int k = (int)__builtin_ctzll(w);
    w &= w - 1;
    int n = ((k >> 1) << 7) + 2 * lane + (k & 1);
    float2 s = sl[n];
    float dx = a.x - s.x, dy = a.y - s.y;
    float t = fmaf(dy, dy, dx * dx) * kNegInvEps + vb[n];
    s_l += __expf(t);
  }
  float ssum = wave_reduce_sum(s_l);
  if (lane == 0) u[row] = (ssum == 0.0f) ? 1.0e9f : -__logf(ssum);
}

// v[col] = !sv ? 0 : -log(sum exp(t) + cc); +1e9 if both empty.
__global__ __launch_bounds__(256) void lse_col_kernel(
    const float2* __restrict__ slm, const float2* __restrict__ tlm,
    const unsigned long long* __restrict__ col_bm,
    const int* __restrict__ smask, const int* __restrict__ ecnt,
    const float* __restrict__ u, float* __restrict__ v)
{
  const int lane = threadIdx.x & 63;
  const int col  = blockIdx.x * 4 + (threadIdx.x >> 6);
  if (!smask[col]) { if (lane == 0) v[col] = 0.0f; return; }
  const int b = col >> 12;
  unsigned long long w = col_bm[(size_t)col * 64 + lane];
  const float2 a = slm[col];
  const float2* __restrict__ tl = tlm + (size_t)b * MM;
  const float*  __restrict__ ub = u + (size_t)b * MM;
  float s_l = 0.0f;
  while (w) {
    int k = (int)__builtin_ctzll(w);
    w &= w - 1;
    int m = ((k >> 1) << 7) + 2 * lane + (k & 1);
    float2 s = tl[m];
    float dx = a.x - s.x, dy = a.y - s.y;
    float t = fmaf(dy, dy, dx * dx) * kNegInvEps + ub[m];
    s_l += __expf(t);
  }
  float ssum = wave_reduce_sum(s_l);
  if (lane == 0) {
    float tot = ssum + (float)ecnt[b];   // contamination entries are exp(0)=1
    v[col] = (tot == 0.0f) ? 1.0e9f : -__logf(tot);
  }
}

// out[row,:] = sum_j attn_j * feats[n_j,:], one block per row.
// XCD-affine swizzle: row = (xcd>>1)*4096 + slot*2 + (xcd&1) so each XCD's
// L2 caches only its own batch's 2MB of feats.
// Phase 1: 256 threads extract the row's bitmap (thread t owns the
// (t&3)-th 16-bit quarter of word t>>2), compute attn, append to LDS via
// atomic slot. Phase 2: 8 groups x 32 lanes gather feats float4.
__global__ __launch_bounds__(256) void output3_kernel(
    const float2* __restrict__ tlm, const float2* __restrict__ slm,
    const unsigned long long* __restrict__ row_bm,
    const float* __restrict__ u, const float* __restrict__ v,
    const float* __restrict__ feats, float* __restrict__ out)
{
  __shared__ float s_attn[1024];
  __shared__ unsigned short s_id[1024];
  __shared__ float4 s_red[256];
  __shared__ int s_cnt;

  const int xcd  = blockIdx.x & 7;
  const int slot = blockIdx.x >> 3;
  const int row  = ((xcd >> 1) << 12) + slot * 2 + (xcd & 1);
  const int tid = threadIdx.x;
  const int b   = row >> 12;
  if (tid == 0) s_cnt = 0;
  __syncthreads();

  {
    const int L  = tid >> 2;
    const int qp = tid & 3;
    unsigned long long w = row_bm[(size_t)row * 64 + L];
    unsigned wq = (unsigned)(unsigned short)(w >> (qp * 16));
    if (wq) {
      const float um = u[row];
      const float2 a = tlm[row];
      const float2* __restrict__ sl = slm + (size_t)b * NN;
      const float*  __restrict__ vb = v + (size_t)b * NN;
      while (wq) {
        int kk = (int)__builtin_ctz(wq);
        wq &= wq - 1;
        int k = qp * 16 + kk;
        int n = ((k >> 1) << 7) + 2 * L + (k & 1);
        float2 s = sl[n];
        float dx = a.x - s.x, dy = a.y - s.y;
        float aw = __expf(fmaf(dy, dy, dx * dx) * kNegInvEps + um + vb[n]);
        int p = atomicAdd(&s_cnt, 1);
        if (p < 1024) { s_attn[p] = aw; s_id[p] = (unsigned short)n; }
      }
    }
  }
  __syncthreads();

  int cnt = s_cnt;
  if (cnt > 1024) cnt = 1024;             // realistic max ~330, never hit
  float4* op = (float4*)(out + (size_t)row * CC);
  if (cnt == 0) {                         // covers !tgt_valid and !has_source
    if (tid < 32) op[tid] = make_float4(0.f, 0.f, 0.f, 0.f);
    return;
  }

  const int g = tid >> 5, l = tid & 31;
  const float4* __restrict__ fb = (const float4*)(feats + (size_t)b * NN * CC);
  float4 acc = make_float4(0.f, 0.f, 0.f, 0.f);
  for (int j = g; j < cnt; j += 8) {
    float aw = s_attn[j];
    int   n  = s_id[j];
    float4 f = fb[(size_t)n * 32 + l];
    acc.x = fmaf(aw, f.x, acc.x);
    acc.y = fmaf(aw, f.y, acc.y);
    acc.z = fmaf(aw, f.z, acc.z);
    acc.w = fmaf(aw, f.w, acc.w);
  }
  s_red[tid] = acc;
  __syncthreads();
  if (tid < 32) {
    float4 r = s_red[tid];
#pragma unroll
    for (int gg = 1; gg < 8; ++gg) {
      float4 p = s_red[gg * 32 + tid];
      r.x += p.x; r.y += p.y; r.z += p.z; r.w += p.w;
    }
    op[tid] = r;
  }
}

// ---------------------------------------------------------------------------
// FALLBACK PATH (round-1 kernels, ~128 KB workspace) — used if ws too small
// ---------------------------------------------------------------------------

__global__ __launch_bounds__(256) void init_v_kernel(float* __restrict__ v) {
  int i = blockIdx.x * 256 + threadIdx.x;
  if (i < BB * NN) v[i] = 0.0f;
}

__global__ __launch_bounds__(256) void u_update_kernel(
    const float* __restrict__ src_locs, const float* __restrict__ tgt_locs,
    const int* __restrict__ src_valid, const int* __restrict__ tgt_valid,
    const float* __restrict__ v, float* __restrict__ u)
{
  const int lane = threadIdx.x & 63;
  const int row  = blockIdx.x * 4 + (threadIdx.x >> 6);
  const int b    = row / MM;
  const float tx = tgt_locs[row * 2 + 0];
  const float ty = tgt_locs[row * 2 + 1];
  const bool  tv = tgt_valid[row] != 0;
  const float2* __restrict__ sl  = (const float2*)(src_locs + (size_t)b * NN * 2);
  const float*  __restrict__ vb  = v + (size_t)b * NN;
  const int*    __restrict__ svb = src_valid + (size_t)b * NN;
  float mx = -3.0e38f;
#pragma unroll 4
  for (int i = 0; i < NN / 64; ++i) {
    int n = i * 64 + lane;
    float2 s = sl[n];
    float dx = tx - s.x, dy = ty - s.y;
    float d2 = dx * dx + dy * dy;
    bool valid = (d2 < kThresh2) & tv & (svb[n] != 0);
    float t = (valid ? d2 * kNegInvEps : kNegInf) + vb[n];
    mx = fmaxf(mx, t);
  }
  mx = wave_reduce_max(mx);
  float s = 0.0f;
#pragma unroll 4
  for (int i = 0; i < NN / 64; ++i) {
    int n = i * 64 + lane;
    float2 sc = sl[n];
    float dx = tx - sc.x, dy = ty - sc.y;
    float d2 = dx * dx + dy * dy;
    bool valid = (d2 < kThresh2) & tv & (svb[n] != 0);
    float t = (valid ? d2 * kNegInvEps : kNegInf) + vb[n];
    s += __expf(t - mx);
  }
  s = wave_reduce_sum(s);
  if (lane == 0) u[row] = -(mx + __logf(s));
}

__global__ __launch_bounds__(256) void v_update_kernel(
    const float* __restrict__ src_locs, const float* __restrict__ tgt_locs,
    const int* __restrict__ src_valid, const int* __restrict__ tgt_valid,
    const float* __restrict__ u, float* __restrict__ v)
{
  const int lane = threadIdx.x & 63;
  const int col  = blockIdx.x * 4 + (threadIdx.x >> 6);
  const int b    = col / NN;
  const float sx = src_locs[col * 2 + 0];
  const float sy = src_locs[col * 2 + 1];
  const bool  sv = src_valid[col] != 0;
  const float2* __restrict__ tl  = (const float2*)(tgt_locs + (size_t)b * MM * 2);
  const float*  __restrict__ ub  = u + (size_t)b * MM;
  const int*    __restrict__ tvb = tgt_valid + (size_t)b * MM;
  float mx = -3.0e38f;
#pragma unroll 4
  for (int i = 0; i < MM / 64; ++i) {
    int m = i * 64 + lane;
    float2 t2 = tl[m];
    float dx = t2.x - sx, dy = t2.y - sy;
    float d2 = dx * dx + dy * dy;
    bool valid = (d2 < kThresh2) & sv & (tvb[m] != 0);
    float t = (valid ? d2 * kNegInvEps : kNegInf) + ub[m];
    mx = fmaxf(mx, t);
  }
  mx = wave_reduce_max(mx);
  float s = 0.0f;
#pragma unroll 4
  for (int i = 0; i < MM / 64; ++i) {
    int m = i * 64 + lane;
    float2 t2 = tl[m];
    float dx = t2.x - sx, dy = t2.y - sy;
    float d2 = dx * dx + dy * dy;
    bool valid = (d2 < kThresh2) & sv & (tvb[m] != 0);
    float t = (valid ? d2 * kNegInvEps : kNegInf) + ub[m];
    s += __expf(t - mx);
  }
  s = wave_reduce_sum(s);
  if (lane == 0) v[col] = sv ? -(mx + __logf(s)) : 0.0f;
}

__global__ __launch_bounds__(256) void output_kernel(
    const float* __restrict__ src_locs, const float* __restrict__ tgt_locs,
    const int* __restrict__ src_valid, const int* __restrict__ tgt_valid,
    const float* __restrict__ u, const float* __restrict__ v,
    const float* __restrict__ feats, float* __restrict__ out)
{
  __shared__ float s_attn[NN];
  __shared__ int   s_idx[NN];
  __shared__ int   s_cnt;
  __shared__ float s_part[CC];
  const int row = blockIdx.x;
  const int b   = row / MM;
  const int tid = threadIdx.x;
  if (tid == 0) s_cnt = 0;
  __syncthreads();
  const float tx = tgt_locs[row * 2 + 0];
  const float ty = tgt_locs[row * 2 + 1];
  const bool  tv = tgt_valid[row] != 0;
  const float um = u[row];
  const float2* __restrict__ sl  = (const float2*)(src_locs + (size_t)b * NN * 2);
  const float*  __restrict__ vb  = v + (size_t)b * NN;
  const int*    __restrict__ svb = src_valid + (size_t)b * NN;
#pragma unroll 4
  for (int i = 0; i < NN / 256; ++i) {
    int n = i * 256 + tid;
    float2 s = sl[n];
    float dx = tx - s.x, dy = ty - s.y;
    float d2 = dx * dx + dy * dy;
    bool valid = (d2 < kThresh2) & tv & (svb[n] != 0);
    if (valid) {
      float a = __expf((d2 * kNegInvEps + um) + vb[n]);
      int p = atomicAdd(&s_cnt, 1);
      s_attn[p] = a;
      s_idx[p]  = n;
    }
  }
  __syncthreads();
  const int cnt = s_cnt;
  const int g = tid >> 7;
  const int c = tid & (CC - 1);
  const float* __restrict__ fb = feats + (size_t)b * NN * CC;
  float acc = 0.0f;
  for (int j = g; j < cnt; j += 2) {
    float a = s_attn[j];
    int   n = s_idx[j];
    acc = fmaf(a, fb[(size_t)n * CC + c], acc);
  }
  if (g == 1) s_part[c] = acc;
  __syncthreads();
  if (g == 0) {
    float r = (cnt > 0) ? (acc + s_part[c]) : 0.0f;
    out[(size_t)row * CC + c] = r;
  }
}

// ---------------------------------------------------------------------------

extern "C" void kernel_launch(void* const* d_in, const int* in_sizes, int n_in,
                              void* d_out, int out_size, void* d_ws, size_t ws_size,
                              hipStream_t stream) {
  const float* feats = (const float*)d_in[0];
  const float* sloc  = (const float*)d_in[1];
  const float* tloc  = (const float*)d_in[2];
  const int*   smask = (const int*)d_in[3];
  const int*   tmask = (const int*)d_in[4];
  float* out = (float*)d_out;

  // workspace layout (fast path): ~17 MB
  char* p = (char*)d_ws;
  float* u_   = (float*)p;            p += (size_t)BB * MM * 4;
  float* v_   = (float*)p;            p += (size_t)BB * NN * 4;
  int* ecnt   = (int*)p;              p += 256;
  float2* slm = (float2*)p;           p += (size_t)BB * NN * 8;
  float2* tlm = (float2*)p;           p += (size_t)BB * MM * 8;
  unsigned long long* row_bm = (unsigned long long*)p; p += (size_t)BB * MM * 64 * 8;
  unsigned long long* col_bm = (unsigned long long*)p; p += (size_t)BB * NN * 64 * 8;
  size_t required = (size_t)(p - (char*)d_ws);

  if (ws_size >= required) {
    prep_kernel<<<(BB * NN + 255) / 256, 256, 0, stream>>>(
        sloc, tloc, smask, tmask, v_, ecnt, slm, tlm);
    sweep7_kernel<<<2 * BB * MM / 16, 256, 0, stream>>>(
        slm, tlm, row_bm, col_bm, ecnt);
    for (int it = 0; it < 3; ++it) {
      lse_row_kernel<<<BB * MM / 4, 256, 0, stream>>>(tlm, slm, row_bm, v_, u_);
      lse_col_kernel<<<BB * NN / 4, 256, 0, stream>>>(slm, tlm, col_bm,
                                                      smask, ecnt, u_, v_);
    }
    output3_kernel<<<BB * MM, 256, 0, stream>>>(tlm, slm, row_bm,
                                                u_, v_, feats, out);
  } else {
    // fallback: round-1 path (dense re-sweeps), needs only 128 KB
    float* u = (float*)d_ws;
    float* v = u + (size_t)BB * MM;
    init_v_kernel<<<(BB * NN + 255) / 256, 256, 0, stream>>>(v);
    for (int it = 0; it < 3; ++it) {
      u_update_kernel<<<BB * MM / 4, 256, 0, stream>>>(sloc, tloc, smask, tmask, v, u);
      v_update_kernel<<<BB * NN / 4, 256, 0, stream>>>(sloc, tloc, smask, tmask, u, v);
    }
    output_kernel<<<BB * MM, 256, 0, stream>>>(sloc, tloc, smask, tmask, u, v, feats, out);
  }
}